// Round 1
// baseline (1108.836 us; speedup 1.0000x reference)
//
#include <hip/hip_runtime.h>

// Problem constants (from reference): M=12, N=8, C=1024, D=64, B=32, S=512
#define M_R   12
#define N_E   8
#define C_DIM 1024
#define D_DIM 64
#define B_SZ  32
#define S_SZ  512
#define TS    128   // s-rows per block
#define PAD   72    // LDS row pitch (bf16 elems): multiple of 8 for 16B-aligned b128

typedef __bf16 bf16x8 __attribute__((ext_vector_type(8)));
typedef float  floatx4 __attribute__((ext_vector_type(4)));

__device__ __forceinline__ unsigned short f2bf(float f) {
    // round-to-nearest-even fp32 -> bf16
    unsigned int u = __float_as_uint(f);
    u += 0x7FFFu + ((u >> 16) & 1u);
    return (unsigned short)(u >> 16);
}

__global__ __launch_bounds__(256) void adapter_fused(
    const float* __restrict__ x,        // [B,S,C]
    const int*   __restrict__ eidx,     // [M,B]
    const float* __restrict__ down_w,   // [M,N,C,D]
    const float* __restrict__ down_b,   // [M,N,D]
    const float* __restrict__ up_w,     // [M,N,D,C]
    float*       __restrict__ out)      // [M,B,S,C]
{
    __shared__ unsigned short Xs[TS * PAD];     // X tile bf16; later Z' tile (aliased)
    __shared__ unsigned short Wt[D_DIM * PAD];  // Wd^T k-chunk; later Wu^T n-chunk
    __shared__ float bias_s[D_DIM];

    const int t    = threadIdx.x;
    const int wave = t >> 6;
    const int lane = t & 63;
    const int l15  = lane & 15;
    const int quad = lane >> 4;
    const int srow = wave * 32;

    const int bid = blockIdx.x;
    const int m  = bid % M_R;      // m innermost: 12 adjacent blocks share an x tile
    const int p  = bid / M_R;
    const int b  = p >> 2;
    const int sc = p & 3;
    const int s0 = sc * TS;

    const int e = eidx[m * B_SZ + b];

    const float* xb   = x      + (b * S_SZ + s0) * C_DIM;
    const float* wd   = down_w + (m * N_E + e) * (C_DIM * D_DIM);
    const float* bias = down_b + (m * N_E + e) * D_DIM;
    const float* wu   = up_w   + (m * N_E + e) * (D_DIM * C_DIM);
    float*       outp = out    + ((m * B_SZ + b) * S_SZ + s0) * C_DIM;

    if (t < D_DIM) bias_s[t] = bias[t];

    floatx4 acc[2][4];
    #pragma unroll
    for (int i = 0; i < 2; ++i)
        #pragma unroll
        for (int j = 0; j < 4; ++j)
            acc[i][j] = (floatx4){0.f, 0.f, 0.f, 0.f};

    // ---------------- GEMM1: Z[128,64] = X[128,1024] * Wd[1024,64] ----------------
    for (int kk = 0; kk < C_DIM; kk += 64) {
        // stage X tile [128 x 64] fp32 -> bf16 LDS (b64 packed writes)
        #pragma unroll
        for (int i = 0; i < 8; ++i) {
            int f4 = i * 256 + t;           // 0..2047 float4s
            int s  = f4 >> 4;               // 0..127
            int k4 = (f4 & 15) << 2;        // 0..60
            float4 v = *(const float4*)(xb + s * C_DIM + kk + k4);
            ushort4 h;
            h.x = f2bf(v.x); h.y = f2bf(v.y); h.z = f2bf(v.z); h.w = f2bf(v.w);
            *(ushort4*)&Xs[s * PAD + k4] = h;
        }
        // stage Wd^T chunk: global [c][d] (d contiguous) -> LDS [d][c]
        #pragma unroll
        for (int i = 0; i < 4; ++i) {
            int f4 = i * 256 + t;           // 0..1023
            int c  = f4 >> 4;               // 0..63
            int d4 = (f4 & 15) << 2;        // 0..60
            float4 v = *(const float4*)(wd + (kk + c) * D_DIM + d4);
            Wt[(d4 + 0) * PAD + c] = f2bf(v.x);
            Wt[(d4 + 1) * PAD + c] = f2bf(v.y);
            Wt[(d4 + 2) * PAD + c] = f2bf(v.z);
            Wt[(d4 + 3) * PAD + c] = f2bf(v.w);
        }
        __syncthreads();

        #pragma unroll
        for (int ks = 0; ks < 64; ks += 32) {
            bf16x8 a0 = *(const bf16x8*)&Xs[(srow +      l15) * PAD + ks + quad * 8];
            bf16x8 a1 = *(const bf16x8*)&Xs[(srow + 16 + l15) * PAD + ks + quad * 8];
            #pragma unroll
            for (int nt = 0; nt < 4; ++nt) {
                bf16x8 bf = *(const bf16x8*)&Wt[(nt * 16 + l15) * PAD + ks + quad * 8];
                acc[0][nt] = __builtin_amdgcn_mfma_f32_16x16x32_bf16(a0, bf, acc[0][nt], 0, 0, 0);
                acc[1][nt] = __builtin_amdgcn_mfma_f32_16x16x32_bf16(a1, bf, acc[1][nt], 0, 0, 0);
            }
        }
        __syncthreads();
    }

    // ---------------- bias + swish, write Z' (bf16) into Xs (aliased) ----------------
    #pragma unroll
    for (int mt = 0; mt < 2; ++mt)
        #pragma unroll
        for (int nt = 0; nt < 4; ++nt)
            #pragma unroll
            for (int r = 0; r < 4; ++r) {
                float z  = acc[mt][nt][r] + bias_s[nt * 16 + l15];
                float sw = z / (1.0f + __expf(-z));
                int s = srow + mt * 16 + quad * 4 + r;   // C/D map: row=quad*4+reg
                int d = nt * 16 + l15;                   //          col=lane&15
                Xs[s * PAD + d] = f2bf(sw);
            }
    __syncthreads();

    // preload GEMM2 A-fragments (Z' rows) once — Zs never changes again
    bf16x8 za[2][2];
    #pragma unroll
    for (int mt = 0; mt < 2; ++mt)
        #pragma unroll
        for (int ki = 0; ki < 2; ++ki)
            za[mt][ki] = *(const bf16x8*)&Xs[(srow + mt * 16 + l15) * PAD + ki * 32 + quad * 8];

    // ---------------- GEMM2: U[128,1024] = Z'[128,64] * Wu[64,1024] ----------------
    for (int ci = 0; ci < 16; ++ci) {
        int c0 = ci * 64;
        // stage Wu^T n-chunk: global [d][c] (c contiguous) -> LDS [c][d]
        #pragma unroll
        for (int i = 0; i < 4; ++i) {
            int f4 = i * 256 + t;
            int d  = f4 >> 4;               // 0..63
            int c4 = (f4 & 15) << 2;        // 0..60
            float4 v = *(const float4*)(wu + d * C_DIM + c0 + c4);
            Wt[(c4 + 0) * PAD + d] = f2bf(v.x);
            Wt[(c4 + 1) * PAD + d] = f2bf(v.y);
            Wt[(c4 + 2) * PAD + d] = f2bf(v.z);
            Wt[(c4 + 3) * PAD + d] = f2bf(v.w);
        }
        __syncthreads();

        floatx4 acc2[2][4];
        #pragma unroll
        for (int i = 0; i < 2; ++i)
            #pragma unroll
            for (int j = 0; j < 4; ++j)
                acc2[i][j] = (floatx4){0.f, 0.f, 0.f, 0.f};

        #pragma unroll
        for (int ki = 0; ki < 2; ++ki) {
            #pragma unroll
            for (int nt = 0; nt < 4; ++nt) {
                bf16x8 bf = *(const bf16x8*)&Wt[(nt * 16 + l15) * PAD + ki * 32 + quad * 8];
                acc2[0][nt] = __builtin_amdgcn_mfma_f32_16x16x32_bf16(za[0][ki], bf, acc2[0][nt], 0, 0, 0);
                acc2[1][nt] = __builtin_amdgcn_mfma_f32_16x16x32_bf16(za[1][ki], bf, acc2[1][nt], 0, 0, 0);
            }
        }

        #pragma unroll
        for (int mt = 0; mt < 2; ++mt)
            #pragma unroll
            for (int nt = 0; nt < 4; ++nt)
                #pragma unroll
                for (int r = 0; r < 4; ++r) {
                    int s = srow + mt * 16 + quad * 4 + r;
                    int c = c0 + nt * 16 + l15;
                    outp[s * C_DIM + c] = acc2[mt][nt][r];
                }
        __syncthreads();
    }
}

extern "C" void kernel_launch(void* const* d_in, const int* in_sizes, int n_in,
                              void* d_out, int out_size, void* d_ws, size_t ws_size,
                              hipStream_t stream) {
    const float* x      = (const float*)d_in[0];
    const int*   eidx   = (const int*)d_in[1];
    const float* down_w = (const float*)d_in[2];
    const float* down_b = (const float*)d_in[3];
    const float* up_w   = (const float*)d_in[4];
    float*       out    = (float*)d_out;

    const int grid = M_R * B_SZ * (S_SZ / TS);   // 12*32*4 = 1536 blocks
    adapter_fused<<<grid, 256, 0, stream>>>(x, eidx, down_w, down_b, up_w, out);
}